// Round 14
// baseline (425.681 us; speedup 1.0000x reference)
//
#include <hip/hip_runtime.h>

#define BB 512
#define TT 1024
#define II 50
#define HH 32
#define CH 16            // steps per chunk (barrier cadence; = MFMA M)
#define NCH (TT / CH)    // 64 chunks
#define RSLOT 32         // ring slots = 2 chunks (double buffer)

typedef float v2f __attribute__((ext_vector_type(2)));
typedef float v4f __attribute__((ext_vector_type(4)));
typedef short v8s __attribute__((ext_vector_type(8)));   // 8 bf16 (4 VGPRs)

__device__ __forceinline__ float fast_rcp(float x) { return __builtin_amdgcn_rcpf(x); }
__device__ __forceinline__ float sigm(float x) { return fast_rcp(1.f + __expf(-x)); }
__device__ __forceinline__ float tanh_(float x) {
    return 1.f - 2.f * fast_rcp(1.f + __expf(2.f * x));   // saturates correctly
}
__device__ __forceinline__ short bf16rne(float f) {      // fp32 -> bf16 RNE
    unsigned u = __float_as_uint(f);
    u += 0x7FFF + ((u >> 16) & 1);
    return (short)(u >> 16);
}
// read lane l's value of v (wave-uniform result, lands in SGPR)
__device__ __forceinline__ float rlane(float v, int l) {
    return __int_as_float(__builtin_amdgcn_readlane(__float_as_int(v), l));
}

// Cross-half (lane ^ 32) SUM via v_permlane32_swap: pure-VALU, off the LDS
// pipe. Returned pair contains {own,partner} in either convention, so
// r0+r1 is convention-independent. partner = xhalf_sum(x) - x.
#if __has_builtin(__builtin_amdgcn_permlane32_swap)
typedef unsigned v2u __attribute__((ext_vector_type(2)));
__device__ __forceinline__ float xhalf_sum(float p) {
    v2u r = __builtin_amdgcn_permlane32_swap(__float_as_uint(p),
                                             __float_as_uint(p), false, false);
    return __uint_as_float(r.x) + __uint_as_float(r.y);
}
#else
__device__ __forceinline__ float xhalf_sum(float p) {
    return p + __shfl_xor(p, 32, 64);
}
#endif

// d_out is poisoned before every launch: init every element to the combined
// FC bias b_comb = fc3_w @ fc1_b + fc3_b (fc1->fc3 is affine-affine; dropout
// is identity in eval). The scan kernel atomicAdds partial dots on top.
__global__ void init_out_kernel(float* __restrict__ out,
                                const float* __restrict__ fc1_b,
                                const float* __restrict__ fc3_w,
                                const float* __restrict__ fc3_b,
                                int n) {
    int idx = blockIdx.x * blockDim.x + threadIdx.x;
    float b = fc3_b[0];
    #pragma unroll
    for (int k = 0; k < 64; ++k) b += fc3_w[k] * fc1_b[k];
    if (idx < n) out[idx] = b;
}

// One workgroup (384 threads = 6 waves) per PAIR of batches.
// R5: 1 block/CU needed for single-round launch. R6/R9 (measured): wave->SIMD
// is round-robin (wave_id%4); consumers must be one-per-SIMD -> 450->315us.
// R9 residual: 738 cy/step = ~620 chain + ~118 producer co-tenancy.
// THIS ROUND: kill the hst LDS round-trip (~150-240 cy on-chain). Each
// consumer wave is single-direction -> h[0..31] is WAVE-UNIFORM -> broadcast
// via 32x v_readlane into scalar regs (VALU, low latency) instead of LDS.
//   Consumer lanes (k=lane&31, gh=lane>>5): gh=0 owns gates {i,f} of unit k,
//   gh=1 owns {g,o}; full K=32 per lane (32 pk_fma). Gate activations are
//   computed ONCE per gate via branchless sigm/tanh unification:
//     act = fma(sigm(z*m), m, a),  m=1,a=0 (sigm) | m=2,a=-1 (tanh)
//   then exchanged across gh-halves with permlane sum-minus-own. Trans ops
//   per lane: 10 -> 4. No hst array, no per-step memory clobber (no
//   cross-step memory deps remain -> compiler free to pipeline).
//   waves 0..3 = consumers: sb = w>>1, dir = w&1 (one per SIMD)
//   waves 4,5  = producers: sb = w-4 (share SIMD0/1; ~25% issue duty)
// Producer wave: ih projection for BOTH dirs of its sub-batch via bf16 MFMA
//   (32 MFMA / 16-step chunk), plus deferred-FC flush + atomicAdd.
// Ring layout (per step-slot, 256 floats): col = d*128 + cidx(gate);
//   cidx: i_k->2k, f_k->2k+1, g_k->64+2k, o_k->64+2k+1. Consumer lane reads
//   ONE b64: {z_i,z_f} at d*128+2k (gh=0) or {z_g,z_o} at d*128+64+2k (gh=1).
// Bias is seeded in the owning lane's accumulator (each gate owned once).
// MFMA layouts (guide-verified m89/m118/m120):
//   A (16x32): m=lane&15, k=(lane>>4)*8+j     (8 bf16/lane)
//   B (32x16): n=lane&15, k=(lane>>4)*8+j
//   D (16x16): m=(lane>>4)*4+reg, n=lane&15   (4 fp32/lane)
__global__ void __launch_bounds__(384, 1) lstm_pc_kernel(
    const float* __restrict__ x,
    const float* __restrict__ w_ih_f, const float* __restrict__ w_hh_f,
    const float* __restrict__ b_ih_f, const float* __restrict__ b_hh_f,
    const float* __restrict__ w_ih_r, const float* __restrict__ w_hh_r,
    const float* __restrict__ b_ih_r, const float* __restrict__ b_hh_r,
    const float* __restrict__ fc1_w, const float* __restrict__ fc3_w,
    float* __restrict__ out)
{
    __shared__ float ringF[2][RSLOT * 256];     // 64 KB: per-step gate projections
    __shared__ float hbuf[2][2][HH][65];        // 33.3 KB: deferred FC partials
    // total ~97.3 KB > 80 KB -> exactly 1 block/CU (required, see R5)

    const int tid  = threadIdx.x;
    const int lane = tid & 63;
    const int wave = tid >> 6;            // 0..5
    const int is_prod = (wave >= 4);
    const int sb   = is_prod ? (wave - 4) : (wave >> 1);
    const int b    = blockIdx.x * 2 + sb;
    float* outb = out + (size_t)b * TT;
    float* ring = ringF[sb];

    if (is_prod) {
        // ================= PRODUCER (MFMA ih projection, both dirs) =========
        const float* xb = x + (size_t)b * TT * II;
        const int nl = lane & 15;         // A: m / B: n / D: n
        const int q  = lane >> 4;         // quad 0..3
        const float* wih[2] = {w_ih_f, w_ih_r};

        // B fragments (persistent): Bf[d][nt][kf], n = nt*16+nl, k = kf*32+q*8+j
        v8s Bf[2][8][2];
        #pragma unroll
        for (int d = 0; d < 2; ++d)
            #pragma unroll
            for (int nt = 0; nt < 8; ++nt) {
                const int n = nt * 16 + nl;
                #pragma unroll
                for (int kf = 0; kf < 2; ++kf)
                    #pragma unroll
                    for (int j = 0; j < 8; ++j) {
                        const int k = kf * 32 + q * 8 + j;
                        Bf[d][nt][kf][j] = (k < II) ? bf16rne(wih[d][n * II + k])
                                                    : (short)0;
                    }
            }

        // gate g -> interleaved ring column
        auto cidx = [](int g) -> int {
            return (g < 32) ? 2 * g
                 : (g < 64) ? 2 * (g - 32) + 1
                 : (g < 96) ? 64 + 2 * (g - 64)
                            : 64 + 2 * (g - 96) + 1;
        };

        // produce chunk c for both dirs: fills ring slots c*CH .. c*CH+15
        auto produce_chunk = [&](int c) {
            #pragma unroll
            for (int d = 0; d < 2; ++d) {
                const int S = c * CH + nl;             // this lane's A-row step
                const int t = d ? (TT - 1 - S) : S;
                const float* xr = xb + (size_t)t * II;
                v8s A0, A1;
                #pragma unroll
                for (int j = 0; j < 8; ++j) A0[j] = bf16rne(xr[q * 8 + j]);
                #pragma unroll
                for (int j = 0; j < 8; ++j) {
                    const int k = 32 + q * 8 + j;
                    A1[j] = (k < II) ? bf16rne(xr[k]) : (short)0;
                }
                #pragma unroll
                for (int nt = 0; nt < 8; ++nt) {
                    v4f acc = {0.f, 0.f, 0.f, 0.f};
                    acc = __builtin_amdgcn_mfma_f32_16x16x32_bf16(A0, Bf[d][nt][0], acc, 0, 0, 0);
                    acc = __builtin_amdgcn_mfma_f32_16x16x32_bf16(A1, Bf[d][nt][1], acc, 0, 0, 0);
                    const int col = d * 128 + cidx(nt * 16 + nl);
                    #pragma unroll
                    for (int r = 0; r < 4; ++r) {
                        const int slot = (c * CH + q * 4 + r) & (RSLOT - 1);
                        ring[slot * 256 + col] = acc[r];
                    }
                }
            }
        };
        // flush chunk m: 16 outputs per dir; lanes 0..31 (d = lane>>4)
        auto flush = [&](int m) {
            if (lane < 32) {
                const int d   = lane >> 4;
                const int idx = lane & 15;
                const int ti  = m * CH + idx;
                const int col = ti & 63;
                float d0 = 0.f, d1 = 0.f, d2 = 0.f, d3 = 0.f;
                #pragma unroll
                for (int k = 0; k < HH; k += 4) {
                    d0 += hbuf[sb][d][k    ][col];
                    d1 += hbuf[sb][d][k + 1][col];
                    d2 += hbuf[sb][d][k + 2][col];
                    d3 += hbuf[sb][d][k + 3][col];
                }
                const int t = d ? (TT - 1 - ti) : ti;
                atomicAdd(&outb[t], (d0 + d1) + (d2 + d3));
            }
        };

        produce_chunk(0);
        __syncthreads();
        for (int n = 0; n < NCH; ++n) {
            if (n + 1 < NCH) produce_chunk(n + 1);
            if (n >= 1) flush(n - 1);
            __syncthreads();
        }
        flush(NCH - 1);
    } else {
        // ================= CONSUMER (fp32 recurrence, dir = wave&1) ========
        const int d  = wave & 1;          // 0 fwd, 1 rev
        const int k  = lane & 31;         // hidden unit
        const int gh = lane >> 5;         // gate-half: 0 -> {i,f}, 1 -> {g,o}
        const float* w_hh = d ? w_hh_r : w_hh_f;
        const float* bi   = d ? b_ih_r : b_ih_f;
        const float* bh   = d ? b_hh_r : b_hh_f;

        // this lane's two gate rows (full K=32 each):
        const int rowA = gh ? (64 + k) : k;         // g : i
        const int rowB = gh ? (96 + k) : (32 + k);  // o : f
        v2f wpA[16], wpB[16];
        #pragma unroll
        for (int j = 0; j < 16; ++j) {
            wpA[j].x = w_hh[rowA * HH + 2 * j];
            wpA[j].y = w_hh[rowA * HH + 2 * j + 1];
            wpB[j].x = w_hh[rowB * HH + 2 * j];
            wpB[j].y = w_hh[rowB * HH + 2 * j + 1];
        }
        const float bA = bi[rowA] + bh[rowA];
        const float bB = bi[rowB] + bh[rowB];
        // sigm/tanh unifier: act = fma(sigm(z*m), m, a)
        const float mm = gh ? 2.f : 1.f;
        const float aa = gh ? -1.f : 0.f;

        // fused FC weight for hidden unit j = d*32 + k
        float wc = 0.f;
        {
            const int j = d * HH + k;
            #pragma unroll
            for (int n = 0; n < 64; ++n) wc += fc3_w[n] * fc1_w[n * 64 + j];
        }

        float c = 0.f;
        float h = 0.f;                    // h(-1) = 0, lives in a register

        __syncthreads();                  // matches producer's prologue barrier

        for (int n = 0; n < NCH; ++n) {
            const int slot0 = (n & 1) * CH;
            const int col0  = (n & 3) * CH;
            #pragma unroll
            for (int u = 0; u < CH; ++u) {
                // x-projection pair for this lane's two gates (off-chain)
                const v2f xz = *(const v2f*)&ring[(slot0 + u) * 256 + d * 128
                                                  + gh * 64 + 2 * k];

                // h(t-1) broadcast: 32 readlanes -> wave-uniform scalars
                float hs[32];
                #pragma unroll
                for (int j = 0; j < 32; ++j) hs[j] = rlane(h, j);

                v2f aA = (v2f){bA, 0.f};
                v2f aB = (v2f){bB, 0.f};
                #pragma unroll
                for (int j = 0; j < 16; ++j) {
                    const v2f hp = {hs[2 * j], hs[2 * j + 1]};
                    aA = __builtin_elementwise_fma(hp, wpA[j], aA);
                    aB = __builtin_elementwise_fma(hp, wpB[j], aB);
                }
                const float zA = xz.x + aA.x + aA.y;
                const float zB = xz.y + aB.x + aB.y;

                // own-gate activations (gate computed exactly once per wave):
                //   gh0: actA = sigm(z_i), actB = sigm(z_f)
                //   gh1: actA = tanh(z_g), actB = sigm(z_o)
                const float actA = fmaf(sigm(zA * mm), mm, aa);
                const float actB = sigm(zB);

                // exchange activated gates across gh halves (VALU permlane)
                const float pA = xhalf_sum(actA) - actA;   // partner's actA
                const float pB = xhalf_sum(actB) - actB;   // partner's actB

                const float si = gh ? pA   : actA;   // sigm(z_i)
                const float tg = gh ? actA : pA;     // tanh(z_g)
                const float sf = gh ? pB   : actB;   // sigm(z_f)
                const float so = gh ? actB : pB;     // sigm(z_o)

                c = fmaf(sf, c, si * tg);
                h = so * tanh_(c);

                hbuf[sb][d][k][col0 + u] = h * wc;   // deferred FC (gh-dup ok)
            }
            __syncthreads();
        }
    }
}

extern "C" void kernel_launch(void* const* d_in, const int* in_sizes, int n_in,
                              void* d_out, int out_size, void* d_ws, size_t ws_size,
                              hipStream_t stream) {
    const float* x      = (const float*)d_in[0];
    const float* w_ih_f = (const float*)d_in[1];
    const float* w_hh_f = (const float*)d_in[2];
    const float* b_ih_f = (const float*)d_in[3];
    const float* b_hh_f = (const float*)d_in[4];
    const float* w_ih_r = (const float*)d_in[5];
    const float* w_hh_r = (const float*)d_in[6];
    const float* b_ih_r = (const float*)d_in[7];
    const float* b_hh_r = (const float*)d_in[8];
    const float* fc1_w  = (const float*)d_in[9];
    const float* fc1_b  = (const float*)d_in[10];
    const float* fc3_w  = (const float*)d_in[11];
    const float* fc3_b  = (const float*)d_in[12];
    float* out = (float*)d_out;

    const int n = BB * TT;
    init_out_kernel<<<(n + 255) / 256, 256, 0, stream>>>(out, fc1_b, fc3_w, fc3_b, n);

    // 256 workgroups = batch pairs; 6 waves each. ~97KB LDS -> exactly one
    // block per CU; 256 blocks = 256 CUs = single round, all work resident.
    lstm_pc_kernel<<<BB / 2, 384, 0, stream>>>(
        x, w_ih_f, w_hh_f, b_ih_f, b_hh_f,
        w_ih_r, w_hh_r, b_ih_r, b_hh_r,
        fc1_w, fc3_w, out);
}